// Round 1
// baseline (607.254 us; speedup 1.0000x reference)
//
#include <hip/hip_runtime.h>

// VTrace: per-batch-column backward linear recurrence.
//   is      = exp(tlp - blp)
//   c = rho = min(1, is)                       (RHO == CIS == 1.0)
//   delta_s = c_s * (r_s + g*V[s+1] - V[s])
//   a_s     = delta_s + g * c_s * a_{s+1},  a_S = 0
//   vtrace  = V + [a; 0]
// Outputs concatenated: vtrace (S+1,B) then clipped_rhos (S,B), both f32.

constexpr int   S_LEN = 512;
constexpr int   BATCH = 65536;
constexpr float GAMMA = 0.99f;

__global__ void __launch_bounds__(256)
vtrace_kernel(const float* __restrict__ V,     // (S+1, B)
              const float* __restrict__ R,     // (S, B)
              const float* __restrict__ TLP,   // (S, B)
              const float* __restrict__ BLP,   // (S, B)
              float* __restrict__ out_vtrace,  // (S+1, B)
              float* __restrict__ out_rho)     // (S, B)
{
    const int b = blockIdx.x * blockDim.x + threadIdx.x;

    // Pointers start at the last row; walk backward by -B each step.
    const float* pV   = V          + (size_t)S_LEN       * BATCH + b;
    const float* pR   = R          + (size_t)(S_LEN - 1) * BATCH + b;
    const float* pT   = TLP        + (size_t)(S_LEN - 1) * BATCH + b;
    const float* pB   = BLP        + (size_t)(S_LEN - 1) * BATCH + b;
    float*       pOut = out_vtrace + (size_t)S_LEN       * BATCH + b;
    float*       pRho = out_rho    + (size_t)(S_LEN - 1) * BATCH + b;

    float vnext = *pV;       // V[S]
    *pOut = vnext;           // vtrace[S] = V[S]  (a_S = 0)

    float a = 0.0f;
    #pragma unroll 4
    for (int s = S_LEN - 1; s >= 0; --s) {
        pV -= BATCH; pOut -= BATCH;
        const float v  = *pV;
        const float r  = *pR;  pR -= BATCH;
        const float t  = *pT;  pT -= BATCH;
        const float bl = *pB;  pB -= BATCH;

        const float is = __expf(t - bl);
        const float c  = fminf(1.0f, is);

        // delta = c * (r + GAMMA*vnext - v)
        const float delta = c * fmaf(GAMMA, vnext, r - v);
        // a = delta + GAMMA * c * a
        a = fmaf(GAMMA * c, a, delta);

        *pRho = c;  pRho -= BATCH;
        *pOut = v + a;
        vnext = v;
    }
}

extern "C" void kernel_launch(void* const* d_in, const int* in_sizes, int n_in,
                              void* d_out, int out_size, void* d_ws, size_t ws_size,
                              hipStream_t stream) {
    const float* V   = (const float*)d_in[0];  // target_value (S+1, B)
    const float* R   = (const float*)d_in[1];  // rewards (S, B)
    const float* TLP = (const float*)d_in[2];  // target_log_policy (S, B)
    const float* BLP = (const float*)d_in[3];  // behaviour_log_policy (S, B)

    float* out_vtrace = (float*)d_out;
    float* out_rho    = out_vtrace + (size_t)(S_LEN + 1) * BATCH;

    const int block = 256;
    const int grid  = BATCH / block;  // 65536 / 256 = 256 blocks
    vtrace_kernel<<<grid, block, 0, stream>>>(V, R, TLP, BLP, out_vtrace, out_rho);
}